// Round 7
// baseline (383.686 us; speedup 1.0000x reference)
//
#include <hip/hip_runtime.h>
#include <math.h>

#define B_ 16
#define N_ 16384
#define C_ 256
#define H_ 128
#define K_ 11468   // int(16384 * 0.7)
#define G_ ((B_ * N_) / 16)

typedef __attribute__((ext_vector_type(8))) short s16x8;
typedef __attribute__((ext_vector_type(4))) float f32x4;
typedef __attribute__((ext_vector_type(4))) unsigned int u32x4;

__device__ __forceinline__ unsigned short f2bf(float f) {
  unsigned u = __builtin_bit_cast(unsigned, f);
  return (unsigned short)((u + 0x7FFFu + ((u >> 16) & 1u)) >> 16);  // RNE
}
// order-preserving map fp32 -> uint32 (no NaNs expected)
__device__ __forceinline__ unsigned fkey(float f) {
  unsigned u = __builtin_bit_cast(unsigned, f);
  return (u & 0x80000000u) ? ~u : (u | 0x80000000u);
}

// branch-free GELU: Winitzki erf approx (max abs err ~1.2e-4), ~14 VALU ops,
// vs ocml erff's ~85 (both divergent branches + exp call). Score perturbation
// ~1e-4 << the ~8e-4 bf16-input noise we already carry.
__device__ __forceinline__ float gelu_fast(float h) {
  const float t = 0.5f * h * h;                 // z^2, z = h/sqrt(2)
  const float u = 0.147f * t;
  const float num = t * (1.2732395f + u);       // z^2*(4/pi + a z^2)
  const float den = 1.0f + u;
  const float r = num * __builtin_amdgcn_rcpf(den);
  const float e = __builtin_amdgcn_exp2f(r * -1.44269504f);   // exp(-r)
  const float s = __builtin_amdgcn_sqrtf(fmaxf(1.0f - e, 0.0f));
  const unsigned sgn = __builtin_bit_cast(unsigned, h) & 0x80000000u;
  const float erfv = __builtin_bit_cast(float, __builtin_bit_cast(unsigned, s) | sgn);
  return 0.5f * h * (1.0f + erfv);
}

// ---- w1 fp32 [C][H] -> bf16 [H][C] with XOR-swizzled 16B chunks (LDS-ready) ----
// chunk (r, c16) stored at chunk position (c16 ^ (r & 31)) within row r.
__global__ void k_prep(const float* __restrict__ w1, unsigned short* __restrict__ w1sw) {
  int i = blockIdx.x * blockDim.x + threadIdx.x;  // i = c*H + r over w1
  if (i < C_ * H_) {
    int c = i / H_, r = i % H_;
    int c16 = c >> 3, j = c & 7;
    w1sw[r * 256 + ((c16 ^ (r & 31)) << 3) + j] = f2bf(w1[i]);
  }
}

// ---------------- fused scorer: scores = fc2(gelu(fc1(tokens))) ----------------
// 768-thread blocks (12 waves): launch_bounds forces VGPR<=168 (3 waves/SIMD) --
// enough for the ~130-reg live set (no spill) and 3x round-6's residency.
__global__ __launch_bounds__(768) void k_score(
    const float* __restrict__ tokens, const unsigned short* __restrict__ w1sw,
    const float* __restrict__ b1, const float* __restrict__ w2,
    const float* __restrict__ b2, float* __restrict__ scores_out) {
  __shared__ unsigned short lds[H_ * C_];  // 64 KB, swizzled bf16 W1^T

  {
    const f32x4* src = reinterpret_cast<const f32x4*>(w1sw);
    f32x4* dst = reinterpret_cast<f32x4*>(lds);
    for (int i = threadIdx.x; i < (H_ * C_ / 8); i += 768) dst[i] = src[i];
  }
  __syncthreads();

  const int lane = threadIdx.x & 63;
  const int l15 = lane & 15;
  const int l4 = lane >> 4;
  const int wid = (blockIdx.x * blockDim.x + threadIdx.x) >> 6;
  const int nw = (gridDim.x * blockDim.x) >> 6;

  for (int g = wid; g < G_; g += nw) {
    const float* tp = tokens + (size_t)(g * 16 + l15) * C_ + l4 * 8;

    f32x4 acc[8];
#pragma unroll
    for (int nb = 0; nb < 8; ++nb) acc[nb] = (f32x4){0.f, 0.f, 0.f, 0.f};

    // one K-slice: pack 8 fp32 -> bf16 (truncation) and do 8 MFMAs
    auto step = [&](int kk, const f32x4& w0, const f32x4& w1v) {
      u32x4 a;
      a[0] = __builtin_amdgcn_perm(__builtin_bit_cast(unsigned, w0[1]),
                                   __builtin_bit_cast(unsigned, w0[0]), 0x07060302u);
      a[1] = __builtin_amdgcn_perm(__builtin_bit_cast(unsigned, w0[3]),
                                   __builtin_bit_cast(unsigned, w0[2]), 0x07060302u);
      a[2] = __builtin_amdgcn_perm(__builtin_bit_cast(unsigned, w1v[1]),
                                   __builtin_bit_cast(unsigned, w1v[0]), 0x07060302u);
      a[3] = __builtin_amdgcn_perm(__builtin_bit_cast(unsigned, w1v[3]),
                                   __builtin_bit_cast(unsigned, w1v[2]), 0x07060302u);
      const int e0 = (((l4 + kk * 4) ^ l15) << 3);  // ushort offset of swizzled chunk
#pragma unroll
      for (int nb = 0; nb < 8; ++nb) {
        const int off = (nb & 1) ? (e0 ^ 128) : e0;  // odd nb: row|16 -> toggle chunk bit4
        s16x8 bf = *reinterpret_cast<const s16x8*>(lds + nb * 4096 + l15 * 256 + off);
        acc[nb] = __builtin_amdgcn_mfma_f32_16x16x32_bf16(
            __builtin_bit_cast(s16x8, a), bf, acc[nb], 0, 0, 0);
      }
    };

    // rotated v[8]: 8 loads in flight, refill pairs as they die (~130-reg live set)
    f32x4 v[8];
#pragma unroll
    for (int kk = 0; kk < 4; ++kk) {
      v[2 * kk] = *reinterpret_cast<const f32x4*>(tp + kk * 32);
      v[2 * kk + 1] = *reinterpret_cast<const f32x4*>(tp + kk * 32 + 4);
    }
    step(0, v[0], v[1]);
    step(1, v[2], v[3]);
    v[0] = *reinterpret_cast<const f32x4*>(tp + 4 * 32);
    v[1] = *reinterpret_cast<const f32x4*>(tp + 4 * 32 + 4);
    v[2] = *reinterpret_cast<const f32x4*>(tp + 5 * 32);
    v[3] = *reinterpret_cast<const f32x4*>(tp + 5 * 32 + 4);
    step(2, v[4], v[5]);
    step(3, v[6], v[7]);
    v[4] = *reinterpret_cast<const f32x4*>(tp + 6 * 32);
    v[5] = *reinterpret_cast<const f32x4*>(tp + 6 * 32 + 4);
    v[6] = *reinterpret_cast<const f32x4*>(tp + 7 * 32);
    v[7] = *reinterpret_cast<const f32x4*>(tp + 7 * 32 + 4);
    step(4, v[0], v[1]);
    step(5, v[2], v[3]);
    step(6, v[4], v[5]);
    step(7, v[6], v[7]);

    // epilogue: + b1, fast GELU, dot w2; D layout: col=lane&15, row=(lane>>4)*4+r
    float p[4] = {0.f, 0.f, 0.f, 0.f};
#pragma unroll
    for (int nb = 0; nb < 8; ++nb) {
      const float b1v = b1[nb * 16 + l15];
      const float w2v = w2[nb * 16 + l15];
#pragma unroll
      for (int r = 0; r < 4; ++r) {
        p[r] += gelu_fast(acc[nb][r] + b1v) * w2v;
      }
    }
    const float b2v = b2[0];
#pragma unroll
    for (int r = 0; r < 4; ++r) {
      float s = p[r];
      s += __shfl_xor(s, 1);
      s += __shfl_xor(s, 2);
      s += __shfl_xor(s, 4);
      s += __shfl_xor(s, 8);
      p[r] = s + b2v;
    }
    if (l15 == 0) {
      const int rb = g * 16 + l4 * 4;
#pragma unroll
      for (int r = 0; r < 4; ++r) scores_out[rb + r] = p[r];
    }
  }
}

// ---------------- block-wide exclusive scan over 1024 threads ----------------
__device__ unsigned block_exscan_1024(unsigned v, volatile unsigned* wsum) {
  const int lane = threadIdx.x & 63;
  const int w = threadIdx.x >> 6;  // 0..15
  unsigned x = v;
#pragma unroll
  for (int d = 1; d < 64; d <<= 1) {
    unsigned t = __shfl_up(x, d);
    if (lane >= d) x += t;
  }
  if (lane == 63) wsum[w] = x;
  __syncthreads();
  if (threadIdx.x == 0) {
    unsigned s = 0;
    for (int i = 0; i < 16; ++i) {
      unsigned t = wsum[i];
      wsum[i] = s;
      s += t;
    }
  }
  __syncthreads();
  unsigned r = wsum[w] + x - v;  // exclusive
  __syncthreads();               // protect wsum for a subsequent call
  return r;
}

// ---------------- per-row top-K via radix select + stable compaction ----------------
__global__ __launch_bounds__(1024) void k_select(const float* __restrict__ scores_f,
                                                 int* __restrict__ kept,
                                                 float* __restrict__ out_idx) {
  __shared__ unsigned hist[256];
  __shared__ unsigned wsum[16];
  __shared__ unsigned sh_prefix, sh_rk;
  const int b = blockIdx.x;
  const int tid = threadIdx.x;
  const float* sp = scores_f + (size_t)b * N_;

  unsigned prefix = 0;
  unsigned rk = K_;  // elements still needed
  for (int pass = 0; pass < 4; ++pass) {
    const int shift = 24 - pass * 8;
    if (tid < 256) hist[tid] = 0;
    __syncthreads();
    const unsigned pmask = pass ? (0xFFFFFFFFu << (shift + 8)) : 0u;
    for (int i = tid; i < N_; i += 1024) {
      unsigned k = fkey(sp[i]);
      if ((k & pmask) == prefix) atomicAdd(&hist[(k >> shift) & 255u], 1u);
    }
    __syncthreads();
    // parallel bin search: suffix-sum via reversed block scan
    unsigned h = (tid < 256) ? hist[255 - tid] : 0u;
    unsigned s = block_exscan_1024(h, wsum);  // s = count of keys in bins > (255-tid)
    if (tid < 256 && s < rk && s + h >= rk) {
      sh_prefix = prefix | ((unsigned)(255 - tid) << shift);
      sh_rk = rk - s;
    }
    __syncthreads();
    prefix = sh_prefix;
    rk = sh_rk;
    __syncthreads();
  }
  const unsigned Tkey = prefix;   // K-th largest key
  const unsigned need = rk;       // how many ==Tkey to keep (lowest indices first)

  // stable compaction in index order; thread owns 16 consecutive indices
  const int i0 = tid * 16;
  unsigned neq = 0;
  for (int j = 0; j < 16; ++j) {
    unsigned k = fkey(sp[i0 + j]);
    neq += (k == Tkey);
  }
  unsigned eq_base = block_exscan_1024(neq, wsum);

  unsigned kcnt = 0;
  {
    unsigned eqr = eq_base;
    for (int j = 0; j < 16; ++j) {
      unsigned k = fkey(sp[i0 + j]);
      bool kp = (k > Tkey) || ((k == Tkey) && (eqr < need));
      eqr += (k == Tkey);
      kcnt += kp;
    }
  }
  unsigned pos = block_exscan_1024(kcnt, wsum);
  {
    unsigned eqr = eq_base;
    for (int j = 0; j < 16; ++j) {
      unsigned k = fkey(sp[i0 + j]);
      bool kp = (k > Tkey) || ((k == Tkey) && (eqr < need));
      eqr += (k == Tkey);
      if (kp) {
        kept[(size_t)b * K_ + pos] = i0 + j;
        out_idx[(size_t)b * K_ + pos] = (float)(i0 + j);
        ++pos;
      }
    }
  }
}

// ---------------- gather kept token rows (fp32 -> fp32) ----------------
__global__ __launch_bounds__(256) void k_gather(const float* __restrict__ tokens,
                                                const int* __restrict__ kept,
                                                float* __restrict__ outp) {
  const int wid = (blockIdx.x * blockDim.x + threadIdx.x) >> 6;  // one wave per row
  const int lane = threadIdx.x & 63;
  if (wid >= B_ * K_) return;
  const int b = wid / K_;
  const int idx = kept[wid];
  const f32x4 v = *reinterpret_cast<const f32x4*>(tokens + ((size_t)b * N_ + idx) * C_ + lane * 4);
  *reinterpret_cast<f32x4*>(outp + (size_t)wid * C_ + lane * 4) = v;
}

extern "C" void kernel_launch(void* const* d_in, const int* in_sizes, int n_in,
                              void* d_out, int out_size, void* d_ws, size_t ws_size,
                              hipStream_t stream) {
  const float* tokens = (const float*)d_in[0];
  const float* w1 = (const float*)d_in[1];
  const float* b1 = (const float*)d_in[2];
  const float* w2 = (const float*)d_in[3];
  const float* b2 = (const float*)d_in[4];

  float* out = (float*)d_out;
  float* out_pruned = out;                                  // B*K*C fp32
  float* out_idx = out + (size_t)B_ * K_ * C_;              // B*K fp32
  float* out_scores = out_idx + (size_t)B_ * K_;            // B*N fp32

  char* ws = (char*)d_ws;
  unsigned short* w1sw = (unsigned short*)ws;               // 64 KB swizzled bf16
  int* kept = (int*)(ws + 0x10000);                         // B*K int32

  k_prep<<<dim3((C_ * H_ + 255) / 256), dim3(256), 0, stream>>>(w1, w1sw);
  k_score<<<dim3(640), dim3(768), 0, stream>>>(tokens, w1sw, b1, w2, b2, out_scores);
  k_select<<<dim3(B_), dim3(1024), 0, stream>>>(out_scores, kept, out_idx);
  k_gather<<<dim3((B_ * K_ + 3) / 4), dim3(256), 0, stream>>>(tokens, kept, out_pruned);
}

// Round 8
// 195.146 us; speedup vs baseline: 1.9661x; 1.9661x over previous
//
#include <hip/hip_runtime.h>
#include <math.h>

#define B_ 16
#define N_ 16384
#define C_ 256
#define H_ 128
#define K_ 11468   // int(16384 * 0.7)
#define G_ ((B_ * N_) / 16)

typedef __attribute__((ext_vector_type(8))) short s16x8;
typedef __attribute__((ext_vector_type(4))) float f32x4;
typedef __attribute__((ext_vector_type(4))) unsigned int u32x4;

__device__ __forceinline__ unsigned short f2bf(float f) {
  unsigned u = __builtin_bit_cast(unsigned, f);
  return (unsigned short)((u + 0x7FFFu + ((u >> 16) & 1u)) >> 16);  // RNE
}
// order-preserving map fp32 -> uint32 (no NaNs expected)
__device__ __forceinline__ unsigned fkey(float f) {
  unsigned u = __builtin_bit_cast(unsigned, f);
  return (u & 0x80000000u) ? ~u : (u | 0x80000000u);
}

// branch-free GELU: Winitzki erf approx (max abs err ~1.2e-4), ~14 VALU ops.
__device__ __forceinline__ float gelu_fast(float h) {
  const float t = 0.5f * h * h;                 // z^2, z = h/sqrt(2)
  const float u = 0.147f * t;
  const float num = t * (1.2732395f + u);       // z^2*(4/pi + a z^2)
  const float den = 1.0f + u;
  const float r = num * __builtin_amdgcn_rcpf(den);
  const float e = __builtin_amdgcn_exp2f(r * -1.44269504f);   // exp(-r)
  const float s = __builtin_amdgcn_sqrtf(fmaxf(1.0f - e, 0.0f));
  const unsigned sgn = __builtin_bit_cast(unsigned, h) & 0x80000000u;
  const float erfv = __builtin_bit_cast(float, __builtin_bit_cast(unsigned, s) | sgn);
  return 0.5f * h * (1.0f + erfv);
}

// ---- w1 fp32 [C][H] -> bf16 [H][C] with XOR-swizzled 16B chunks (LDS-ready) ----
// chunk (r, c16) stored at chunk position (c16 ^ (r & 31)) within row r.
__global__ void k_prep(const float* __restrict__ w1, unsigned short* __restrict__ w1sw) {
  int i = blockIdx.x * blockDim.x + threadIdx.x;  // i = c*H + r over w1
  if (i < C_ * H_) {
    int c = i / H_, r = i % H_;
    int c16 = c >> 3, j = c & 7;
    w1sw[r * 256 + ((c16 ^ (r & 31)) << 3) + j] = f2bf(w1[i]);
  }
}

// ---------------- fused scorer: scores = fc2(gelu(fc1(tokens))) ----------------
// 256-thread blocks (the ONLY config where the backend allocates >128 VGPRs —
// rounds 4/5/7 proved 512/768-thr blocks get squeezed to 64/84 regs + scratch
// spill). Live set shrunk structurally: pack all A-fragments first (loads die),
// then nb-outer with a single acc[4] and immediate gelu+dot consumption.
__global__ __launch_bounds__(256) void k_score(
    const float* __restrict__ tokens, const unsigned short* __restrict__ w1sw,
    const float* __restrict__ b1, const float* __restrict__ w2,
    const float* __restrict__ b2, float* __restrict__ scores_out) {
  __shared__ unsigned short lds[H_ * C_];  // 64 KB, swizzled bf16 W1^T

  {
    const f32x4* src = reinterpret_cast<const f32x4*>(w1sw);
    f32x4* dst = reinterpret_cast<f32x4*>(lds);
    const int t = threadIdx.x;
#pragma unroll
    for (int i = 0; i < 16; ++i) dst[t + i * 256] = src[t + i * 256];
  }
  __syncthreads();

  const int lane = threadIdx.x & 63;
  const int l15 = lane & 15;
  const int l4 = lane >> 4;
  const int wid = (blockIdx.x * blockDim.x + threadIdx.x) >> 6;
  const int nw = (gridDim.x * blockDim.x) >> 6;

  // hoisted epilogue constants (L1-hot, but keep them in regs across the loop)
  float b1v[8], w2v[8];
#pragma unroll
  for (int nb = 0; nb < 8; ++nb) {
    b1v[nb] = b1[nb * 16 + l15];
    w2v[nb] = w2[nb * 16 + l15];
  }
  const float b2v = b2[0];

  for (int g = wid; g < G_; g += nw) {
    const float* tp = tokens + (size_t)(g * 16 + l15) * C_ + l4 * 8;

    // (1) issue all 16 16B loads (deep MLP queue, ~16 KB/CU in flight)
    f32x4 v[16];
#pragma unroll
    for (int kk = 0; kk < 8; ++kk) {
      v[2 * kk] = *reinterpret_cast<const f32x4*>(tp + kk * 32);
      v[2 * kk + 1] = *reinterpret_cast<const f32x4*>(tp + kk * 32 + 4);
    }
    // (2) pack everything to bf16 A-fragments; the 64 load regs die here
    u32x4 a[8];
#pragma unroll
    for (int kk = 0; kk < 8; ++kk) {
      a[kk][0] = __builtin_amdgcn_perm(__builtin_bit_cast(unsigned, v[2 * kk][1]),
                                       __builtin_bit_cast(unsigned, v[2 * kk][0]), 0x07060302u);
      a[kk][1] = __builtin_amdgcn_perm(__builtin_bit_cast(unsigned, v[2 * kk][3]),
                                       __builtin_bit_cast(unsigned, v[2 * kk][2]), 0x07060302u);
      a[kk][2] = __builtin_amdgcn_perm(__builtin_bit_cast(unsigned, v[2 * kk + 1][1]),
                                       __builtin_bit_cast(unsigned, v[2 * kk + 1][0]), 0x07060302u);
      a[kk][3] = __builtin_amdgcn_perm(__builtin_bit_cast(unsigned, v[2 * kk + 1][3]),
                                       __builtin_bit_cast(unsigned, v[2 * kk + 1][2]), 0x07060302u);
    }

    // (3) nb-outer: one acc[4] at a time, consumed immediately
    float p[4] = {0.f, 0.f, 0.f, 0.f};
#pragma unroll
    for (int nb = 0; nb < 8; ++nb) {
      f32x4 acc = (f32x4){0.f, 0.f, 0.f, 0.f};
#pragma unroll
      for (int kk = 0; kk < 8; ++kk) {
        const int e0 = (((l4 + kk * 4) ^ l15) << 3);
        const int off = (nb & 1) ? (e0 ^ 128) : e0;  // odd nb: row|16 -> toggle chunk bit4
        s16x8 bf = *reinterpret_cast<const s16x8*>(lds + nb * 4096 + l15 * 256 + off);
        acc = __builtin_amdgcn_mfma_f32_16x16x32_bf16(
            __builtin_bit_cast(s16x8, a[kk]), bf, acc, 0, 0, 0);
      }
#pragma unroll
      for (int r = 0; r < 4; ++r) p[r] += gelu_fast(acc[r] + b1v[nb]) * w2v[nb];
    }

#pragma unroll
    for (int r = 0; r < 4; ++r) {
      float s = p[r];
      s += __shfl_xor(s, 1);
      s += __shfl_xor(s, 2);
      s += __shfl_xor(s, 4);
      s += __shfl_xor(s, 8);
      p[r] = s + b2v;
    }
    if (l15 == 0) {
      const int rb = g * 16 + l4 * 4;
#pragma unroll
      for (int r = 0; r < 4; ++r) scores_out[rb + r] = p[r];
    }
  }
}

// ---------------- block-wide exclusive scan over 1024 threads ----------------
__device__ unsigned block_exscan_1024(unsigned v, volatile unsigned* wsum) {
  const int lane = threadIdx.x & 63;
  const int w = threadIdx.x >> 6;  // 0..15
  unsigned x = v;
#pragma unroll
  for (int d = 1; d < 64; d <<= 1) {
    unsigned t = __shfl_up(x, d);
    if (lane >= d) x += t;
  }
  if (lane == 63) wsum[w] = x;
  __syncthreads();
  if (threadIdx.x == 0) {
    unsigned s = 0;
    for (int i = 0; i < 16; ++i) {
      unsigned t = wsum[i];
      wsum[i] = s;
      s += t;
    }
  }
  __syncthreads();
  unsigned r = wsum[w] + x - v;  // exclusive
  __syncthreads();               // protect wsum for a subsequent call
  return r;
}

// ---------------- per-row top-K via radix select + stable compaction ----------------
__global__ __launch_bounds__(1024) void k_select(const float* __restrict__ scores_f,
                                                 int* __restrict__ kept,
                                                 float* __restrict__ out_idx) {
  __shared__ unsigned hist[256];
  __shared__ unsigned wsum[16];
  __shared__ unsigned sh_prefix, sh_rk;
  const int b = blockIdx.x;
  const int tid = threadIdx.x;
  const float* sp = scores_f + (size_t)b * N_;

  unsigned prefix = 0;
  unsigned rk = K_;  // elements still needed
  for (int pass = 0; pass < 4; ++pass) {
    const int shift = 24 - pass * 8;
    if (tid < 256) hist[tid] = 0;
    __syncthreads();
    const unsigned pmask = pass ? (0xFFFFFFFFu << (shift + 8)) : 0u;
    for (int i = tid; i < N_; i += 1024) {
      unsigned k = fkey(sp[i]);
      if ((k & pmask) == prefix) atomicAdd(&hist[(k >> shift) & 255u], 1u);
    }
    __syncthreads();
    // parallel bin search: suffix-sum via reversed block scan
    unsigned h = (tid < 256) ? hist[255 - tid] : 0u;
    unsigned s = block_exscan_1024(h, wsum);  // s = count of keys in bins > (255-tid)
    if (tid < 256 && s < rk && s + h >= rk) {
      sh_prefix = prefix | ((unsigned)(255 - tid) << shift);
      sh_rk = rk - s;
    }
    __syncthreads();
    prefix = sh_prefix;
    rk = sh_rk;
    __syncthreads();
  }
  const unsigned Tkey = prefix;   // K-th largest key
  const unsigned need = rk;       // how many ==Tkey to keep (lowest indices first)

  // stable compaction in index order; thread owns 16 consecutive indices
  const int i0 = tid * 16;
  unsigned neq = 0;
  for (int j = 0; j < 16; ++j) {
    unsigned k = fkey(sp[i0 + j]);
    neq += (k == Tkey);
  }
  unsigned eq_base = block_exscan_1024(neq, wsum);

  unsigned kcnt = 0;
  {
    unsigned eqr = eq_base;
    for (int j = 0; j < 16; ++j) {
      unsigned k = fkey(sp[i0 + j]);
      bool kp = (k > Tkey) || ((k == Tkey) && (eqr < need));
      eqr += (k == Tkey);
      kcnt += kp;
    }
  }
  unsigned pos = block_exscan_1024(kcnt, wsum);
  {
    unsigned eqr = eq_base;
    for (int j = 0; j < 16; ++j) {
      unsigned k = fkey(sp[i0 + j]);
      bool kp = (k > Tkey) || ((k == Tkey) && (eqr < need));
      eqr += (k == Tkey);
      if (kp) {
        kept[(size_t)b * K_ + pos] = i0 + j;
        out_idx[(size_t)b * K_ + pos] = (float)(i0 + j);
        ++pos;
      }
    }
  }
}

// ---------------- gather kept token rows (fp32 -> fp32) ----------------
__global__ __launch_bounds__(256) void k_gather(const float* __restrict__ tokens,
                                                const int* __restrict__ kept,
                                                float* __restrict__ outp) {
  const int wid = (blockIdx.x * blockDim.x + threadIdx.x) >> 6;  // one wave per row
  const int lane = threadIdx.x & 63;
  if (wid >= B_ * K_) return;
  const int b = wid / K_;
  const int idx = kept[wid];
  const f32x4 v = *reinterpret_cast<const f32x4*>(tokens + ((size_t)b * N_ + idx) * C_ + lane * 4);
  *reinterpret_cast<f32x4*>(outp + (size_t)wid * C_ + lane * 4) = v;
}

extern "C" void kernel_launch(void* const* d_in, const int* in_sizes, int n_in,
                              void* d_out, int out_size, void* d_ws, size_t ws_size,
                              hipStream_t stream) {
  const float* tokens = (const float*)d_in[0];
  const float* w1 = (const float*)d_in[1];
  const float* b1 = (const float*)d_in[2];
  const float* w2 = (const float*)d_in[3];
  const float* b2 = (const float*)d_in[4];

  float* out = (float*)d_out;
  float* out_pruned = out;                                  // B*K*C fp32
  float* out_idx = out + (size_t)B_ * K_ * C_;              // B*K fp32
  float* out_scores = out_idx + (size_t)B_ * K_;            // B*N fp32

  char* ws = (char*)d_ws;
  unsigned short* w1sw = (unsigned short*)ws;               // 64 KB swizzled bf16
  int* kept = (int*)(ws + 0x10000);                         // B*K int32

  k_prep<<<dim3((C_ * H_ + 255) / 256), dim3(256), 0, stream>>>(w1, w1sw);
  k_score<<<dim3(1024), dim3(256), 0, stream>>>(tokens, w1sw, b1, w2, b2, out_scores);
  k_select<<<dim3(B_), dim3(1024), 0, stream>>>(out_scores, kept, out_idx);
  k_gather<<<dim3((B_ * K_ + 3) / 4), dim3(256), 0, stream>>>(tokens, kept, out_pruned);
}

// Round 9
// 180.789 us; speedup vs baseline: 2.1223x; 1.0794x over previous
//
#include <hip/hip_runtime.h>
#include <math.h>

#define B_ 16
#define N_ 16384
#define C_ 256
#define H_ 128
#define K_ 11468   // int(16384 * 0.7)
#define G_ ((B_ * N_) / 16)

typedef __attribute__((ext_vector_type(8))) short s16x8;
typedef __attribute__((ext_vector_type(4))) float f32x4;
typedef __attribute__((ext_vector_type(4))) unsigned int u32x4;

__device__ __forceinline__ unsigned short f2bf(float f) {
  unsigned u = __builtin_bit_cast(unsigned, f);
  return (unsigned short)((u + 0x7FFFu + ((u >> 16) & 1u)) >> 16);  // RNE
}
// order-preserving map fp32 -> uint32 (no NaNs expected)
__device__ __forceinline__ unsigned fkey(float f) {
  unsigned u = __builtin_bit_cast(unsigned, f);
  return (u & 0x80000000u) ? ~u : (u | 0x80000000u);
}

// branch-free GELU: Winitzki erf approx (max abs err ~1.2e-4), ~14 VALU ops.
__device__ __forceinline__ float gelu_fast(float h) {
  const float t = 0.5f * h * h;                 // z^2, z = h/sqrt(2)
  const float u = 0.147f * t;
  const float num = t * (1.2732395f + u);       // z^2*(4/pi + a z^2)
  const float den = 1.0f + u;
  const float r = num * __builtin_amdgcn_rcpf(den);
  const float e = __builtin_amdgcn_exp2f(r * -1.44269504f);   // exp(-r)
  const float s = __builtin_amdgcn_sqrtf(fmaxf(1.0f - e, 0.0f));
  const unsigned sgn = __builtin_bit_cast(unsigned, h) & 0x80000000u;
  const float erfv = __builtin_bit_cast(float, __builtin_bit_cast(unsigned, s) | sgn);
  return 0.5f * h * (1.0f + erfv);
}

// ---- w1 fp32 [C][H] -> bf16 [H][C] with XOR-swizzled 16B chunks (LDS-ready) ----
// chunk (r, c16) stored at chunk position (c16 ^ (r & 31)) within row r.
__global__ void k_prep(const float* __restrict__ w1, unsigned short* __restrict__ w1sw) {
  int i = blockIdx.x * blockDim.x + threadIdx.x;  // i = c*H + r over w1
  if (i < C_ * H_) {
    int c = i / H_, r = i % H_;
    int c16 = c >> 3, j = c & 7;
    w1sw[r * 256 + ((c16 ^ (r & 31)) << 3) + j] = f2bf(w1[i]);
  }
}

// ---------------- fused scorer: scores = fc2(gelu(fc1(tokens))) ----------------
// 256-thread blocks (backend gives >128 VGPR only here — rounds 4/5/7 proved
// 512/768-thr blocks get 64/84 regs + scratch spill). Round-9 change: software
// prefetch — pack current group's A (loads die), issue NEXT group's 16 loads,
// then MFMA+epilogue. HBM latency hides under ~2500cy of compute per group.
__global__ __launch_bounds__(256) void k_score(
    const float* __restrict__ tokens, const unsigned short* __restrict__ w1sw,
    const float* __restrict__ b1, const float* __restrict__ w2,
    const float* __restrict__ b2, float* __restrict__ scores_out) {
  __shared__ unsigned short lds[H_ * C_];  // 64 KB, swizzled bf16 W1^T

  {
    const f32x4* src = reinterpret_cast<const f32x4*>(w1sw);
    f32x4* dst = reinterpret_cast<f32x4*>(lds);
    const int t = threadIdx.x;
#pragma unroll
    for (int i = 0; i < 16; ++i) dst[t + i * 256] = src[t + i * 256];
  }
  __syncthreads();

  const int lane = threadIdx.x & 63;
  const int l15 = lane & 15;
  const int l4 = lane >> 4;
  const int wid = (blockIdx.x * blockDim.x + threadIdx.x) >> 6;
  const int nw = (gridDim.x * blockDim.x) >> 6;

  // hoisted epilogue constants
  float b1v[8], w2v[8];
#pragma unroll
  for (int nb = 0; nb < 8; ++nb) {
    b1v[nb] = b1[nb * 16 + l15];
    w2v[nb] = w2[nb * 16 + l15];
  }
  const float b2v = b2[0];

  // prologue: issue first group's 16 loads
  f32x4 v[16];
  {
    const float* tp = tokens + (size_t)(wid * 16 + l15) * C_ + l4 * 8;
#pragma unroll
    for (int kk = 0; kk < 8; ++kk) {
      v[2 * kk] = *reinterpret_cast<const f32x4*>(tp + kk * 32);
      v[2 * kk + 1] = *reinterpret_cast<const f32x4*>(tp + kk * 32 + 4);
    }
  }

  for (int g = wid; g < G_; g += nw) {
    // (1) pack current group's loads to bf16 A-fragments; v dies here
    u32x4 a[8];
#pragma unroll
    for (int kk = 0; kk < 8; ++kk) {
      a[kk][0] = __builtin_amdgcn_perm(__builtin_bit_cast(unsigned, v[2 * kk][1]),
                                       __builtin_bit_cast(unsigned, v[2 * kk][0]), 0x07060302u);
      a[kk][1] = __builtin_amdgcn_perm(__builtin_bit_cast(unsigned, v[2 * kk][3]),
                                       __builtin_bit_cast(unsigned, v[2 * kk][2]), 0x07060302u);
      a[kk][2] = __builtin_amdgcn_perm(__builtin_bit_cast(unsigned, v[2 * kk + 1][1]),
                                       __builtin_bit_cast(unsigned, v[2 * kk + 1][0]), 0x07060302u);
      a[kk][3] = __builtin_amdgcn_perm(__builtin_bit_cast(unsigned, v[2 * kk + 1][3]),
                                       __builtin_bit_cast(unsigned, v[2 * kk + 1][2]), 0x07060302u);
    }

    // (2) prefetch NEXT group's 16 loads — land during (3)
    const int gn = g + nw;
    if (gn < G_) {
      const float* tp = tokens + (size_t)(gn * 16 + l15) * C_ + l4 * 8;
#pragma unroll
      for (int kk = 0; kk < 8; ++kk) {
        v[2 * kk] = *reinterpret_cast<const f32x4*>(tp + kk * 32);
        v[2 * kk + 1] = *reinterpret_cast<const f32x4*>(tp + kk * 32 + 4);
      }
    }

    // (3) nb-outer: one acc[4] at a time, consumed immediately
    float p[4] = {0.f, 0.f, 0.f, 0.f};
#pragma unroll
    for (int nb = 0; nb < 8; ++nb) {
      f32x4 acc = (f32x4){0.f, 0.f, 0.f, 0.f};
#pragma unroll
      for (int kk = 0; kk < 8; ++kk) {
        const int e0 = (((l4 + kk * 4) ^ l15) << 3);
        const int off = (nb & 1) ? (e0 ^ 128) : e0;  // odd nb: row|16 -> toggle chunk bit4
        s16x8 bf = *reinterpret_cast<const s16x8*>(lds + nb * 4096 + l15 * 256 + off);
        acc = __builtin_amdgcn_mfma_f32_16x16x32_bf16(
            __builtin_bit_cast(s16x8, a[kk]), bf, acc, 0, 0, 0);
      }
#pragma unroll
      for (int r = 0; r < 4; ++r) p[r] += gelu_fast(acc[r] + b1v[nb]) * w2v[nb];
    }

#pragma unroll
    for (int r = 0; r < 4; ++r) {
      float s = p[r];
      s += __shfl_xor(s, 1);
      s += __shfl_xor(s, 2);
      s += __shfl_xor(s, 4);
      s += __shfl_xor(s, 8);
      p[r] = s + b2v;
    }
    if (l15 == 0) {
      const int rb = g * 16 + l4 * 4;
#pragma unroll
      for (int r = 0; r < 4; ++r) scores_out[rb + r] = p[r];
    }
  }
}

// ---------------- block-wide exclusive scan over 1024 threads ----------------
__device__ unsigned block_exscan_1024(unsigned v, volatile unsigned* wsum) {
  const int lane = threadIdx.x & 63;
  const int w = threadIdx.x >> 6;  // 0..15
  unsigned x = v;
#pragma unroll
  for (int d = 1; d < 64; d <<= 1) {
    unsigned t = __shfl_up(x, d);
    if (lane >= d) x += t;
  }
  if (lane == 63) wsum[w] = x;
  __syncthreads();
  if (threadIdx.x == 0) {
    unsigned s = 0;
    for (int i = 0; i < 16; ++i) {
      unsigned t = wsum[i];
      wsum[i] = s;
      s += t;
    }
  }
  __syncthreads();
  unsigned r = wsum[w] + x - v;  // exclusive
  __syncthreads();               // protect wsum for a subsequent call
  return r;
}

// ---------------- per-row top-K via radix select + stable compaction ----------------
__global__ __launch_bounds__(1024) void k_select(const float* __restrict__ scores_f,
                                                 int* __restrict__ kept,
                                                 float* __restrict__ out_idx) {
  __shared__ unsigned hist[256];
  __shared__ unsigned wsum[16];
  __shared__ unsigned sh_prefix, sh_rk;
  const int b = blockIdx.x;
  const int tid = threadIdx.x;
  const float* sp = scores_f + (size_t)b * N_;

  unsigned prefix = 0;
  unsigned rk = K_;  // elements still needed
  for (int pass = 0; pass < 4; ++pass) {
    const int shift = 24 - pass * 8;
    if (tid < 256) hist[tid] = 0;
    __syncthreads();
    const unsigned pmask = pass ? (0xFFFFFFFFu << (shift + 8)) : 0u;
    for (int i = tid; i < N_; i += 1024) {
      unsigned k = fkey(sp[i]);
      if ((k & pmask) == prefix) atomicAdd(&hist[(k >> shift) & 255u], 1u);
    }
    __syncthreads();
    // parallel bin search: suffix-sum via reversed block scan
    unsigned h = (tid < 256) ? hist[255 - tid] : 0u;
    unsigned s = block_exscan_1024(h, wsum);  // s = count of keys in bins > (255-tid)
    if (tid < 256 && s < rk && s + h >= rk) {
      sh_prefix = prefix | ((unsigned)(255 - tid) << shift);
      sh_rk = rk - s;
    }
    __syncthreads();
    prefix = sh_prefix;
    rk = sh_rk;
    __syncthreads();
  }
  const unsigned Tkey = prefix;   // K-th largest key
  const unsigned need = rk;       // how many ==Tkey to keep (lowest indices first)

  // stable compaction in index order; thread owns 16 consecutive indices
  const int i0 = tid * 16;
  unsigned neq = 0;
  for (int j = 0; j < 16; ++j) {
    unsigned k = fkey(sp[i0 + j]);
    neq += (k == Tkey);
  }
  unsigned eq_base = block_exscan_1024(neq, wsum);

  unsigned kcnt = 0;
  {
    unsigned eqr = eq_base;
    for (int j = 0; j < 16; ++j) {
      unsigned k = fkey(sp[i0 + j]);
      bool kp = (k > Tkey) || ((k == Tkey) && (eqr < need));
      eqr += (k == Tkey);
      kcnt += kp;
    }
  }
  unsigned pos = block_exscan_1024(kcnt, wsum);
  {
    unsigned eqr = eq_base;
    for (int j = 0; j < 16; ++j) {
      unsigned k = fkey(sp[i0 + j]);
      bool kp = (k > Tkey) || ((k == Tkey) && (eqr < need));
      eqr += (k == Tkey);
      if (kp) {
        kept[(size_t)b * K_ + pos] = i0 + j;
        out_idx[(size_t)b * K_ + pos] = (float)(i0 + j);
        ++pos;
      }
    }
  }
}

// ---------------- gather kept token rows (fp32 -> fp32) ----------------
__global__ __launch_bounds__(256) void k_gather(const float* __restrict__ tokens,
                                                const int* __restrict__ kept,
                                                float* __restrict__ outp) {
  const int wid = (blockIdx.x * blockDim.x + threadIdx.x) >> 6;  // one wave per row
  const int lane = threadIdx.x & 63;
  if (wid >= B_ * K_) return;
  const int b = wid / K_;
  const int idx = kept[wid];
  const f32x4 v = *reinterpret_cast<const f32x4*>(tokens + ((size_t)b * N_ + idx) * C_ + lane * 4);
  *reinterpret_cast<f32x4*>(outp + (size_t)wid * C_ + lane * 4) = v;
}

extern "C" void kernel_launch(void* const* d_in, const int* in_sizes, int n_in,
                              void* d_out, int out_size, void* d_ws, size_t ws_size,
                              hipStream_t stream) {
  const float* tokens = (const float*)d_in[0];
  const float* w1 = (const float*)d_in[1];
  const float* b1 = (const float*)d_in[2];
  const float* w2 = (const float*)d_in[3];
  const float* b2 = (const float*)d_in[4];

  float* out = (float*)d_out;
  float* out_pruned = out;                                  // B*K*C fp32
  float* out_idx = out + (size_t)B_ * K_ * C_;              // B*K fp32
  float* out_scores = out_idx + (size_t)B_ * K_;            // B*N fp32

  char* ws = (char*)d_ws;
  unsigned short* w1sw = (unsigned short*)ws;               // 64 KB swizzled bf16
  int* kept = (int*)(ws + 0x10000);                         // B*K int32

  k_prep<<<dim3((C_ * H_ + 255) / 256), dim3(256), 0, stream>>>(w1, w1sw);
  k_score<<<dim3(1024), dim3(256), 0, stream>>>(tokens, w1sw, b1, w2, b2, out_scores);
  k_select<<<dim3(B_), dim3(1024), 0, stream>>>(out_scores, kept, out_idx);
  k_gather<<<dim3((B_ * K_ + 3) / 4), dim3(256), 0, stream>>>(tokens, kept, out_pruned);
}

// Round 10
// 176.108 us; speedup vs baseline: 2.1787x; 1.0266x over previous
//
#include <hip/hip_runtime.h>
#include <math.h>

#define B_ 16
#define N_ 16384
#define C_ 256
#define H_ 128
#define K_ 11468   // int(16384 * 0.7)
#define G_ ((B_ * N_) / 16)

typedef __attribute__((ext_vector_type(8))) short s16x8;
typedef __attribute__((ext_vector_type(4))) float f32x4;
typedef __attribute__((ext_vector_type(4))) unsigned int u32x4;

__device__ __forceinline__ unsigned short f2bf(float f) {
  unsigned u = __builtin_bit_cast(unsigned, f);
  return (unsigned short)((u + 0x7FFFu + ((u >> 16) & 1u)) >> 16);  // RNE
}
// order-preserving map fp32 -> uint32 (no NaNs expected)
__device__ __forceinline__ unsigned fkey(float f) {
  unsigned u = __builtin_bit_cast(unsigned, f);
  return (u & 0x80000000u) ? ~u : (u | 0x80000000u);
}

// branch-free GELU: Winitzki erf approx (max abs err ~1.2e-4), ~14 VALU ops.
__device__ __forceinline__ float gelu_fast(float h) {
  const float t = 0.5f * h * h;                 // z^2, z = h/sqrt(2)
  const float u = 0.147f * t;
  const float num = t * (1.2732395f + u);       // z^2*(4/pi + a z^2)
  const float den = 1.0f + u;
  const float r = num * __builtin_amdgcn_rcpf(den);
  const float e = __builtin_amdgcn_exp2f(r * -1.44269504f);   // exp(-r)
  const float s = __builtin_amdgcn_sqrtf(fmaxf(1.0f - e, 0.0f));
  const unsigned sgn = __builtin_bit_cast(unsigned, h) & 0x80000000u;
  const float erfv = __builtin_bit_cast(float, __builtin_bit_cast(unsigned, s) | sgn);
  return 0.5f * h * (1.0f + erfv);
}

// ---- w1 fp32 [C][H] -> bf16 [H][C] with XOR-swizzled 16B chunks (LDS-ready) ----
// chunk (r, c16) stored at chunk position (c16 ^ (r & 31)) within row r.
__global__ void k_prep(const float* __restrict__ w1, unsigned short* __restrict__ w1sw) {
  int i = blockIdx.x * blockDim.x + threadIdx.x;  // i = c*H + r over w1
  if (i < C_ * H_) {
    int c = i / H_, r = i % H_;
    int c16 = c >> 3, j = c & 7;
    w1sw[r * 256 + ((c16 ^ (r & 31)) << 3) + j] = f2bf(w1[i]);
  }
}

// ---------------- fused scorer: scores = fc2(gelu(fc1(tokens))) ----------------
// 256-thread blocks. Round-10: kk-outer/nb-inner with per-kk A-pack and per-kk
// prefetch refill. Peak live set ~116 regs: v[16](64)+acc[8](32)+a(4)+misc.
// Goal: VGPR<=128 -> 2 waves/SIMD with the 64KB-LDS 2-block ceiling.
__global__ __launch_bounds__(256) void k_score(
    const float* __restrict__ tokens, const unsigned short* __restrict__ w1sw,
    const float* __restrict__ b1, const float* __restrict__ w2,
    const float* __restrict__ b2, float* __restrict__ scores_out) {
  __shared__ unsigned short lds[H_ * C_];  // 64 KB, swizzled bf16 W1^T

  {
    const f32x4* src = reinterpret_cast<const f32x4*>(w1sw);
    f32x4* dst = reinterpret_cast<f32x4*>(lds);
    const int t = threadIdx.x;
#pragma unroll
    for (int i = 0; i < 16; ++i) dst[t + i * 256] = src[t + i * 256];
  }
  __syncthreads();

  const int lane = threadIdx.x & 63;
  const int l15 = lane & 15;
  const int l4 = lane >> 4;
  const int wid = (blockIdx.x * blockDim.x + threadIdx.x) >> 6;
  const int nw = (gridDim.x * blockDim.x) >> 6;

  // prologue: issue first group's 16 loads
  f32x4 v[16];
  {
    const float* tp = tokens + (size_t)(wid * 16 + l15) * C_ + l4 * 8;
#pragma unroll
    for (int kk = 0; kk < 8; ++kk) {
      v[2 * kk] = *reinterpret_cast<const f32x4*>(tp + kk * 32);
      v[2 * kk + 1] = *reinterpret_cast<const f32x4*>(tp + kk * 32 + 4);
    }
  }

  for (int g = wid; g < G_; g += nw) {
    const int gn = g + nw;
    const float* tpn = tokens + (size_t)(gn * 16 + l15) * C_ + l4 * 8;
    const bool pf = (gn < G_);

    f32x4 acc[8];
#pragma unroll
    for (int nb = 0; nb < 8; ++nb) acc[nb] = (f32x4){0.f, 0.f, 0.f, 0.f};

#pragma unroll
    for (int kk = 0; kk < 8; ++kk) {
      // pack this K-slice's A-fragment; v[2kk],v[2kk+1] die here
      u32x4 a;
      a[0] = __builtin_amdgcn_perm(__builtin_bit_cast(unsigned, v[2 * kk][1]),
                                   __builtin_bit_cast(unsigned, v[2 * kk][0]), 0x07060302u);
      a[1] = __builtin_amdgcn_perm(__builtin_bit_cast(unsigned, v[2 * kk][3]),
                                   __builtin_bit_cast(unsigned, v[2 * kk][2]), 0x07060302u);
      a[2] = __builtin_amdgcn_perm(__builtin_bit_cast(unsigned, v[2 * kk + 1][1]),
                                   __builtin_bit_cast(unsigned, v[2 * kk + 1][0]), 0x07060302u);
      a[3] = __builtin_amdgcn_perm(__builtin_bit_cast(unsigned, v[2 * kk + 1][3]),
                                   __builtin_bit_cast(unsigned, v[2 * kk + 1][2]), 0x07060302u);
      // refill the freed slots with next group's loads (spread prefetch)
      if (pf) {
        v[2 * kk] = *reinterpret_cast<const f32x4*>(tpn + kk * 32);
        v[2 * kk + 1] = *reinterpret_cast<const f32x4*>(tpn + kk * 32 + 4);
      }
      const int e0 = (((l4 + kk * 4) ^ l15) << 3);  // swizzled chunk (even nb)
#pragma unroll
      for (int nb = 0; nb < 8; ++nb) {
        const int off = (nb & 1) ? (e0 ^ 128) : e0;  // odd nb: row|16 -> toggle bit4
        s16x8 bf = *reinterpret_cast<const s16x8*>(lds + nb * 4096 + l15 * 256 + off);
        acc[nb] = __builtin_amdgcn_mfma_f32_16x16x32_bf16(
            __builtin_bit_cast(s16x8, a), bf, acc[nb], 0, 0, 0);
      }
    }

    // epilogue: + b1, fast GELU, dot w2 (b1/w2 loads here, L1-hot: frees 16 regs
    // from the hot loop). D layout: col=lane&15, row=(lane>>4)*4+r
    float p[4] = {0.f, 0.f, 0.f, 0.f};
#pragma unroll
    for (int nb = 0; nb < 8; ++nb) {
      const float b1v = b1[nb * 16 + l15];
      const float w2v = w2[nb * 16 + l15];
#pragma unroll
      for (int r = 0; r < 4; ++r) p[r] += gelu_fast(acc[nb][r] + b1v) * w2v;
    }
    const float b2v = b2[0];
#pragma unroll
    for (int r = 0; r < 4; ++r) {
      float s = p[r];
      s += __shfl_xor(s, 1);
      s += __shfl_xor(s, 2);
      s += __shfl_xor(s, 4);
      s += __shfl_xor(s, 8);
      p[r] = s + b2v;
    }
    if (l15 == 0) {
      const int rb = g * 16 + l4 * 4;
#pragma unroll
      for (int r = 0; r < 4; ++r) scores_out[rb + r] = p[r];
    }
  }
}

// ---------------- block-wide exclusive scan over 1024 threads ----------------
__device__ unsigned block_exscan_1024(unsigned v, volatile unsigned* wsum) {
  const int lane = threadIdx.x & 63;
  const int w = threadIdx.x >> 6;  // 0..15
  unsigned x = v;
#pragma unroll
  for (int d = 1; d < 64; d <<= 1) {
    unsigned t = __shfl_up(x, d);
    if (lane >= d) x += t;
  }
  if (lane == 63) wsum[w] = x;
  __syncthreads();
  if (threadIdx.x == 0) {
    unsigned s = 0;
    for (int i = 0; i < 16; ++i) {
      unsigned t = wsum[i];
      wsum[i] = s;
      s += t;
    }
  }
  __syncthreads();
  unsigned r = wsum[w] + x - v;  // exclusive
  __syncthreads();               // protect wsum for a subsequent call
  return r;
}

// ---------------- per-row top-K via radix select + stable compaction ----------------
__global__ __launch_bounds__(1024) void k_select(const float* __restrict__ scores_f,
                                                 int* __restrict__ kept,
                                                 float* __restrict__ out_idx) {
  __shared__ unsigned hist[256];
  __shared__ unsigned wsum[16];
  __shared__ unsigned sh_prefix, sh_rk;
  const int b = blockIdx.x;
  const int tid = threadIdx.x;
  const float* sp = scores_f + (size_t)b * N_;

  unsigned prefix = 0;
  unsigned rk = K_;  // elements still needed
  for (int pass = 0; pass < 4; ++pass) {
    const int shift = 24 - pass * 8;
    if (tid < 256) hist[tid] = 0;
    __syncthreads();
    const unsigned pmask = pass ? (0xFFFFFFFFu << (shift + 8)) : 0u;
    for (int i = tid; i < N_; i += 1024) {
      unsigned k = fkey(sp[i]);
      if ((k & pmask) == prefix) atomicAdd(&hist[(k >> shift) & 255u], 1u);
    }
    __syncthreads();
    // parallel bin search: suffix-sum via reversed block scan
    unsigned h = (tid < 256) ? hist[255 - tid] : 0u;
    unsigned s = block_exscan_1024(h, wsum);  // s = count of keys in bins > (255-tid)
    if (tid < 256 && s < rk && s + h >= rk) {
      sh_prefix = prefix | ((unsigned)(255 - tid) << shift);
      sh_rk = rk - s;
    }
    __syncthreads();
    prefix = sh_prefix;
    rk = sh_rk;
    __syncthreads();
  }
  const unsigned Tkey = prefix;   // K-th largest key
  const unsigned need = rk;       // how many ==Tkey to keep (lowest indices first)

  // stable compaction in index order; thread owns 16 consecutive indices
  const int i0 = tid * 16;
  unsigned neq = 0;
  for (int j = 0; j < 16; ++j) {
    unsigned k = fkey(sp[i0 + j]);
    neq += (k == Tkey);
  }
  unsigned eq_base = block_exscan_1024(neq, wsum);

  unsigned kcnt = 0;
  {
    unsigned eqr = eq_base;
    for (int j = 0; j < 16; ++j) {
      unsigned k = fkey(sp[i0 + j]);
      bool kp = (k > Tkey) || ((k == Tkey) && (eqr < need));
      eqr += (k == Tkey);
      kcnt += kp;
    }
  }
  unsigned pos = block_exscan_1024(kcnt, wsum);
  {
    unsigned eqr = eq_base;
    for (int j = 0; j < 16; ++j) {
      unsigned k = fkey(sp[i0 + j]);
      bool kp = (k > Tkey) || ((k == Tkey) && (eqr < need));
      eqr += (k == Tkey);
      if (kp) {
        kept[(size_t)b * K_ + pos] = i0 + j;
        out_idx[(size_t)b * K_ + pos] = (float)(i0 + j);
        ++pos;
      }
    }
  }
}

// ---------------- gather kept token rows (fp32 -> fp32) ----------------
__global__ __launch_bounds__(256) void k_gather(const float* __restrict__ tokens,
                                                const int* __restrict__ kept,
                                                float* __restrict__ outp) {
  const int wid = (blockIdx.x * blockDim.x + threadIdx.x) >> 6;  // one wave per row
  const int lane = threadIdx.x & 63;
  if (wid >= B_ * K_) return;
  const int b = wid / K_;
  const int idx = kept[wid];
  const f32x4 v = *reinterpret_cast<const f32x4*>(tokens + ((size_t)b * N_ + idx) * C_ + lane * 4);
  *reinterpret_cast<f32x4*>(outp + (size_t)wid * C_ + lane * 4) = v;
}

extern "C" void kernel_launch(void* const* d_in, const int* in_sizes, int n_in,
                              void* d_out, int out_size, void* d_ws, size_t ws_size,
                              hipStream_t stream) {
  const float* tokens = (const float*)d_in[0];
  const float* w1 = (const float*)d_in[1];
  const float* b1 = (const float*)d_in[2];
  const float* w2 = (const float*)d_in[3];
  const float* b2 = (const float*)d_in[4];

  float* out = (float*)d_out;
  float* out_pruned = out;                                  // B*K*C fp32
  float* out_idx = out + (size_t)B_ * K_ * C_;              // B*K fp32
  float* out_scores = out_idx + (size_t)B_ * K_;            // B*N fp32

  char* ws = (char*)d_ws;
  unsigned short* w1sw = (unsigned short*)ws;               // 64 KB swizzled bf16
  int* kept = (int*)(ws + 0x10000);                         // B*K int32

  k_prep<<<dim3((C_ * H_ + 255) / 256), dim3(256), 0, stream>>>(w1, w1sw);
  k_score<<<dim3(1024), dim3(256), 0, stream>>>(tokens, w1sw, b1, w2, b2, out_scores);
  k_select<<<dim3(B_), dim3(1024), 0, stream>>>(out_scores, kept, out_idx);
  k_gather<<<dim3((B_ * K_ + 3) / 4), dim3(256), 0, stream>>>(tokens, kept, out_pruned);
}